// Round 1
// baseline (654.717 us; speedup 1.0000x reference)
//
#include <hip/hip_runtime.h>
#include <hip/hip_bf16.h>

#define TT 4096
#define DD 2048
#define NH 16
#define NKV 4
#define DHD 128
#define NQKV 3072

typedef __attribute__((ext_vector_type(8))) short short8;
typedef __attribute__((ext_vector_type(4))) float f32x4;
typedef __hip_bfloat16 bf16;

// ---------------- cast x -> bf16 ----------------
__global__ void cast_x_kernel(const float* __restrict__ x, bf16* __restrict__ xb, int n) {
    int i = (blockIdx.x * blockDim.x + threadIdx.x) * 4;
    if (i >= n) return;
    float4 v = *(const float4*)(x + i);
    xb[i + 0] = __float2bfloat16(v.x);
    xb[i + 1] = __float2bfloat16(v.y);
    xb[i + 2] = __float2bfloat16(v.z);
    xb[i + 3] = __float2bfloat16(v.w);
}

// ---------------- transpose + cast W (K x N fp32) -> out rows [rowOff..rowOff+N) of (rows x K) bf16 ----------------
__global__ void transpose_cast_kernel(const float* __restrict__ in, bf16* __restrict__ out,
                                      int K, int N, int rowOff) {
    __shared__ float tile[32][33];
    int k0 = blockIdx.x * 32, n0 = blockIdx.y * 32;
    int tx = threadIdx.x, ty = threadIdx.y;
#pragma unroll
    for (int i = 0; i < 4; ++i)
        tile[ty + i * 8][tx] = in[(size_t)(k0 + ty + i * 8) * N + n0 + tx];
    __syncthreads();
#pragma unroll
    for (int i = 0; i < 4; ++i)
        out[(size_t)(rowOff + n0 + ty + i * 8) * K + k0 + tx] = __float2bfloat16(tile[tx][ty + i * 8]);
}

// ---------------- GEMM: A (M x K) bf16 row-major, Bt (N x K) bf16 row-major, C (M x N) ----------------
template <bool OUT_BF16>
__global__ __launch_bounds__(256) void gemm_bt_kernel(const bf16* __restrict__ A,
                                                      const bf16* __restrict__ Bt,
                                                      void* __restrict__ C,
                                                      int M, int N, int K) {
    __shared__ bf16 As[128][40];
    __shared__ bf16 Bs[128][40];
    int bn0 = blockIdx.x * 128, bm0 = blockIdx.y * 128;
    int tid = threadIdx.x;
    int wave = tid >> 6, lane = tid & 63, quad = lane >> 4, l15 = lane & 15;
    int wm = (wave >> 1) * 64, wn = (wave & 1) * 64;
    f32x4 zero = {0.f, 0.f, 0.f, 0.f};
    f32x4 acc[4][4];
#pragma unroll
    for (int i = 0; i < 4; ++i)
#pragma unroll
        for (int j = 0; j < 4; ++j) acc[i][j] = zero;

    for (int k0 = 0; k0 < K; k0 += 32) {
#pragma unroll
        for (int r = 0; r < 2; ++r) {
            int idx = r * 256 + tid;
            int row = idx >> 2, col = (idx & 3) * 8;
            *(short8*)&As[row][col] = *(const short8*)(A + (size_t)(bm0 + row) * K + k0 + col);
            *(short8*)&Bs[row][col] = *(const short8*)(Bt + (size_t)(bn0 + row) * K + k0 + col);
        }
        __syncthreads();
        short8 af[4], bfr[4];
#pragma unroll
        for (int i = 0; i < 4; ++i) af[i] = *(const short8*)&As[wm + i * 16 + l15][quad * 8];
#pragma unroll
        for (int j = 0; j < 4; ++j) bfr[j] = *(const short8*)&Bs[wn + j * 16 + l15][quad * 8];
#pragma unroll
        for (int i = 0; i < 4; ++i)
#pragma unroll
            for (int j = 0; j < 4; ++j)
                acc[i][j] = __builtin_amdgcn_mfma_f32_16x16x32_bf16(af[i], bfr[j], acc[i][j], 0, 0, 0);
        __syncthreads();
    }
#pragma unroll
    for (int i = 0; i < 4; ++i)
#pragma unroll
        for (int j = 0; j < 4; ++j)
#pragma unroll
            for (int r = 0; r < 4; ++r) {
                int row = bm0 + wm + i * 16 + quad * 4 + r;
                int col = bn0 + wn + j * 16 + l15;
                float v = acc[i][j][r];
                if (OUT_BF16)
                    ((bf16*)C)[(size_t)row * N + col] = __float2bfloat16(v);
                else
                    ((float*)C)[(size_t)row * N + col] = v;
            }
}

// ---------------- RoPE + head split. QKV (T x 3072) bf16 -> Qs[H][T][128] (scaled), Ks[HKV][T][128], Vt[HKV][128][T] ----------------
__global__ void rope_split_kernel(const bf16* __restrict__ QKV, bf16* __restrict__ Qs,
                                  bf16* __restrict__ Ks, bf16* __restrict__ Vt) {
    int slot = blockIdx.x * 4 + (threadIdx.x >> 6);
    int d = threadIdx.x & 63;
    int t = slot / 24, c = slot % 24;
    const bf16* base = QKV + (size_t)t * NQKV;
    int off = (c < 16) ? c * 128 : (c < 20) ? 2048 + (c - 16) * 128 : 2560 + (c - 20) * 128;
    float x1 = __bfloat162float(base[off + d]);
    float x2 = __bfloat162float(base[off + 64 + d]);
    float o1, o2;
    if (c < 20) {
        // inv_freq = 10000^(-d/64) = exp(-d * ln(10000)/64)
        float invf = __expf((float)d * -0.14391156831f);
        float ang = (float)t * invf;
        float sn = sinf(ang), cs = cosf(ang);
        o1 = x1 * cs - x2 * sn;
        o2 = x1 * sn + x2 * cs;
    } else {
        o1 = x1;
        o2 = x2;
    }
    if (c < 16) {
        const float scale = 0.08838834764831845f;  // 1/sqrt(128), folded into Q
        o1 *= scale;
        o2 *= scale;
        bf16* dst = Qs + ((size_t)c * TT + t) * DHD;
        dst[d] = __float2bfloat16(o1);
        dst[d + 64] = __float2bfloat16(o2);
    } else if (c < 20) {
        bf16* dst = Ks + ((size_t)(c - 16) * TT + t) * DHD;
        dst[d] = __float2bfloat16(o1);
        dst[d + 64] = __float2bfloat16(o2);
    } else {
        int gg = c - 20;
        Vt[((size_t)gg * DHD + d) * TT + t] = __float2bfloat16(o1);
        Vt[((size_t)gg * DHD + d + 64) * TT + t] = __float2bfloat16(o2);
    }
}

// ---------------- Flash attention: causal, GQA 16 q-heads / 4 kv-heads ----------------
__global__ __launch_bounds__(256) void attn_kernel(const bf16* __restrict__ Qs,
                                                   const bf16* __restrict__ Ks,
                                                   const bf16* __restrict__ Vt,
                                                   bf16* __restrict__ Y) {
    __shared__ bf16 KsL[32][136];    // [key][dh], padded
    __shared__ bf16 VtL[128][40];    // [dh][key], padded
    __shared__ bf16 PsL[4][16][40];  // per wave [qrow][key], padded
    int h = blockIdx.y, qb = blockIdx.x, g = h >> 2;
    int tid = threadIdx.x, wave = tid >> 6, lane = tid & 63, quad = lane >> 4, l15 = lane & 15;
    int qbase = qb * 64 + wave * 16;

    // Q fragments for this wave's 16 rows (A-layout: m=l15, k=quad*8+j), held in regs the whole time
    short8 qf[4];
    const bf16* qptr = Qs + ((size_t)h * TT + qbase + l15) * DHD + quad * 8;
#pragma unroll
    for (int ks = 0; ks < 4; ++ks) qf[ks] = *(const short8*)(qptr + ks * 32);

    f32x4 zero = {0.f, 0.f, 0.f, 0.f};
    f32x4 acc[8];
#pragma unroll
    for (int i = 0; i < 8; ++i) acc[i] = zero;
    float m_i[4] = {-1e30f, -1e30f, -1e30f, -1e30f};
    float l_i[4] = {0.f, 0.f, 0.f, 0.f};

    int ntiles = qb * 2 + 2;
    const bf16* kg = Ks + (size_t)g * TT * DHD;
    const bf16* vg = Vt + (size_t)g * DHD * TT;

    for (int kt = 0; kt < ntiles; ++kt) {
        // stage K tile (32 x 128) and Vt tile (128 x 32)
#pragma unroll
        for (int r = 0; r < 2; ++r) {
            int c = r * 256 + tid;
            int row = c >> 4, col = (c & 15) * 8;
            *(short8*)&KsL[row][col] = *(const short8*)(kg + (size_t)(kt * 32 + row) * DHD + col);
            int vrow = c >> 2, vcol = (c & 3) * 8;
            *(short8*)&VtL[vrow][vcol] = *(const short8*)(vg + (size_t)vrow * TT + kt * 32 + vcol);
        }
        __syncthreads();

        // S = Q K^T (scale already folded into Q)
        f32x4 s[2];
        s[0] = zero;
        s[1] = zero;
#pragma unroll
        for (int nt = 0; nt < 2; ++nt)
#pragma unroll
            for (int ks = 0; ks < 4; ++ks) {
                short8 b = *(const short8*)&KsL[nt * 16 + l15][ks * 32 + quad * 8];
                s[nt] = __builtin_amdgcn_mfma_f32_16x16x32_bf16(qf[ks], b, s[nt], 0, 0, 0);
            }
        // causal mask (C-layout: row = quad*4+r, col = l15)
#pragma unroll
        for (int nt = 0; nt < 2; ++nt) {
            int key = kt * 32 + nt * 16 + l15;
#pragma unroll
            for (int r = 0; r < 4; ++r) {
                int qpos = qbase + quad * 4 + r;
                if (key > qpos) s[nt][r] = -1e30f;
            }
        }
        // online softmax
        float alpha[4];
#pragma unroll
        for (int r = 0; r < 4; ++r) {
            float mt = fmaxf(s[0][r], s[1][r]);
            mt = fmaxf(mt, __shfl_xor(mt, 1, 16));
            mt = fmaxf(mt, __shfl_xor(mt, 2, 16));
            mt = fmaxf(mt, __shfl_xor(mt, 4, 16));
            mt = fmaxf(mt, __shfl_xor(mt, 8, 16));
            float mnew = fmaxf(m_i[r], mt);
            alpha[r] = __expf(m_i[r] - mnew);
            m_i[r] = mnew;
        }
#pragma unroll
        for (int nt = 0; nt < 2; ++nt)
#pragma unroll
            for (int r = 0; r < 4; ++r) s[nt][r] = __expf(s[nt][r] - m_i[r]);
#pragma unroll
        for (int r = 0; r < 4; ++r) {
            float rs = s[0][r] + s[1][r];
            rs += __shfl_xor(rs, 1, 16);
            rs += __shfl_xor(rs, 2, 16);
            rs += __shfl_xor(rs, 4, 16);
            rs += __shfl_xor(rs, 8, 16);
            l_i[r] = l_i[r] * alpha[r] + rs;
        }
#pragma unroll
        for (int d8 = 0; d8 < 8; ++d8)
#pragma unroll
            for (int r = 0; r < 4; ++r) acc[d8][r] *= alpha[r];

        // P: C-layout -> LDS -> A-layout (wave-local round trip)
#pragma unroll
        for (int nt = 0; nt < 2; ++nt)
#pragma unroll
            for (int r = 0; r < 4; ++r)
                PsL[wave][quad * 4 + r][nt * 16 + l15] = __float2bfloat16(s[nt][r]);
        asm volatile("s_waitcnt lgkmcnt(0)" ::: "memory");
        short8 pf = *(const short8*)&PsL[wave][l15][quad * 8];

        // O += P V   (B from Vt: B^T layout, contiguous along key)
#pragma unroll
        for (int d8 = 0; d8 < 8; ++d8) {
            short8 b = *(const short8*)&VtL[d8 * 16 + l15][quad * 8];
            acc[d8] = __builtin_amdgcn_mfma_f32_16x16x32_bf16(pf, b, acc[d8], 0, 0, 0);
        }
        __syncthreads();
    }
    // epilogue: O / l, write Y[t][h*128+dh] bf16
#pragma unroll
    for (int r = 0; r < 4; ++r) l_i[r] = 1.0f / l_i[r];
#pragma unroll
    for (int d8 = 0; d8 < 8; ++d8)
#pragma unroll
        for (int r = 0; r < 4; ++r) {
            int t = qbase + quad * 4 + r;
            int dh = d8 * 16 + l15;
            Y[(size_t)t * DD + h * DHD + dh] = __float2bfloat16(acc[d8][r] * l_i[r]);
        }
}

extern "C" void kernel_launch(void* const* d_in, const int* in_sizes, int n_in,
                              void* d_out, int out_size, void* d_ws, size_t ws_size,
                              hipStream_t stream) {
    const float* x = (const float*)d_in[0];
    const float* Wq = (const float*)d_in[1];
    const float* Wk = (const float*)d_in[2];
    const float* Wv = (const float*)d_in[3];
    const float* Wo = (const float*)d_in[4];

    char* ws = (char*)d_ws;
    size_t off = 0;
    auto alloc = [&](size_t bytes) {
        void* p = ws + off;
        off += (bytes + 255) & ~(size_t)255;
        return p;
    };
    bf16* xb = (bf16*)alloc((size_t)TT * DD * 2);
    bf16* Wt = (bf16*)alloc((size_t)NQKV * DD * 2);   // [Wq^T | Wk^T | Wv^T] rows, each row K=2048
    bf16* Wot = (bf16*)alloc((size_t)DD * DD * 2);    // Wo^T
    bf16* QKVb = (bf16*)alloc((size_t)TT * NQKV * 2);
    bf16* Qs = (bf16*)alloc((size_t)NH * TT * DHD * 2);
    bf16* Ksb = (bf16*)alloc((size_t)NKV * TT * DHD * 2);
    bf16* Vtb = (bf16*)alloc((size_t)NKV * DHD * TT * 2);
    bf16* Yb = (bf16*)alloc((size_t)TT * DD * 2);

    cast_x_kernel<<<(TT * DD / 4 + 255) / 256, 256, 0, stream>>>(x, xb, TT * DD);
    dim3 tb(32, 8);
    transpose_cast_kernel<<<dim3(DD / 32, DD / 32), tb, 0, stream>>>(Wq, Wt, DD, DD, 0);
    transpose_cast_kernel<<<dim3(DD / 32, 512 / 32), tb, 0, stream>>>(Wk, Wt, DD, 512, 2048);
    transpose_cast_kernel<<<dim3(DD / 32, 512 / 32), tb, 0, stream>>>(Wv, Wt, DD, 512, 2560);
    transpose_cast_kernel<<<dim3(DD / 32, DD / 32), tb, 0, stream>>>(Wo, Wot, DD, DD, 0);

    gemm_bt_kernel<true><<<dim3(NQKV / 128, TT / 128), 256, 0, stream>>>(xb, Wt, QKVb, TT, NQKV, DD);
    rope_split_kernel<<<TT * 24 / 4, 256, 0, stream>>>(QKVb, Qs, Ksb, Vtb);
    attn_kernel<<<dim3(TT / 64, NH), 256, 0, stream>>>(Qs, Ksb, Vtb, Yb);
    gemm_bt_kernel<false><<<dim3(DD / 128, TT / 128), 256, 0, stream>>>(Yb, Wot, d_out, TT, DD, DD);
}

// Round 2
// 460.011 us; speedup vs baseline: 1.4233x; 1.4233x over previous
//
#include <hip/hip_runtime.h>
#include <hip/hip_bf16.h>

#define TT 4096
#define DD 2048
#define NH 16
#define NKV 4
#define DHD 128
#define NQKV 3072

typedef __attribute__((ext_vector_type(8))) short short8;
typedef __attribute__((ext_vector_type(4))) float f32x4;
typedef __hip_bfloat16 bf16;

// ---------------- cast x -> bf16 ----------------
__global__ void cast_x_kernel(const float* __restrict__ x, bf16* __restrict__ xb, int n) {
    int i = (blockIdx.x * blockDim.x + threadIdx.x) * 4;
    if (i >= n) return;
    float4 v = *(const float4*)(x + i);
    xb[i + 0] = __float2bfloat16(v.x);
    xb[i + 1] = __float2bfloat16(v.y);
    xb[i + 2] = __float2bfloat16(v.z);
    xb[i + 3] = __float2bfloat16(v.w);
}

// ---------------- transpose + cast W (K x N fp32) -> out rows [rowOff..rowOff+N) of (rows x K) bf16 ----------------
__global__ void transpose_cast_kernel(const float* __restrict__ in, bf16* __restrict__ out,
                                      int K, int N, int rowOff) {
    __shared__ float tile[32][33];
    int k0 = blockIdx.x * 32, n0 = blockIdx.y * 32;
    int tx = threadIdx.x, ty = threadIdx.y;
#pragma unroll
    for (int i = 0; i < 4; ++i)
        tile[ty + i * 8][tx] = in[(size_t)(k0 + ty + i * 8) * N + n0 + tx];
    __syncthreads();
#pragma unroll
    for (int i = 0; i < 4; ++i)
        out[(size_t)(rowOff + n0 + ty + i * 8) * K + k0 + tx] = __float2bfloat16(tile[tx][ty + i * 8]);
}

// ---------------- GEMM: A (M x K) bf16 row-major, Bt (N x K) bf16 row-major, C (M x N) ----------------
template <bool OUT_BF16>
__global__ __launch_bounds__(256) void gemm_bt_kernel(const bf16* __restrict__ A,
                                                      const bf16* __restrict__ Bt,
                                                      void* __restrict__ C,
                                                      int M, int N, int K) {
    __shared__ bf16 As[128][40];
    __shared__ bf16 Bs[128][40];
    int bn0 = blockIdx.x * 128, bm0 = blockIdx.y * 128;
    int tid = threadIdx.x;
    int wave = tid >> 6, lane = tid & 63, quad = lane >> 4, l15 = lane & 15;
    int wm = (wave >> 1) * 64, wn = (wave & 1) * 64;
    f32x4 zero = {0.f, 0.f, 0.f, 0.f};
    f32x4 acc[4][4];
#pragma unroll
    for (int i = 0; i < 4; ++i)
#pragma unroll
        for (int j = 0; j < 4; ++j) acc[i][j] = zero;

    for (int k0 = 0; k0 < K; k0 += 32) {
#pragma unroll
        for (int r = 0; r < 2; ++r) {
            int idx = r * 256 + tid;
            int row = idx >> 2, col = (idx & 3) * 8;
            *(short8*)&As[row][col] = *(const short8*)(A + (size_t)(bm0 + row) * K + k0 + col);
            *(short8*)&Bs[row][col] = *(const short8*)(Bt + (size_t)(bn0 + row) * K + k0 + col);
        }
        __syncthreads();
        short8 af[4], bfr[4];
#pragma unroll
        for (int i = 0; i < 4; ++i) af[i] = *(const short8*)&As[wm + i * 16 + l15][quad * 8];
#pragma unroll
        for (int j = 0; j < 4; ++j) bfr[j] = *(const short8*)&Bs[wn + j * 16 + l15][quad * 8];
#pragma unroll
        for (int i = 0; i < 4; ++i)
#pragma unroll
            for (int j = 0; j < 4; ++j)
                acc[i][j] = __builtin_amdgcn_mfma_f32_16x16x32_bf16(af[i], bfr[j], acc[i][j], 0, 0, 0);
        __syncthreads();
    }
#pragma unroll
    for (int i = 0; i < 4; ++i)
#pragma unroll
        for (int j = 0; j < 4; ++j)
#pragma unroll
            for (int r = 0; r < 4; ++r) {
                int row = bm0 + wm + i * 16 + quad * 4 + r;
                int col = bn0 + wn + j * 16 + l15;
                float v = acc[i][j][r];
                if (OUT_BF16)
                    ((bf16*)C)[(size_t)row * N + col] = __float2bfloat16(v);
                else
                    ((float*)C)[(size_t)row * N + col] = v;
            }
}

// ---------------- RoPE + head split. QKV (T x 3072) bf16 -> Qs[H][T][128] (scaled by 1/sqrt(128)*log2e), Ks[HKV][T][128], Vt[HKV][128][T] ----------------
__global__ void rope_split_kernel(const bf16* __restrict__ QKV, bf16* __restrict__ Qs,
                                  bf16* __restrict__ Ks, bf16* __restrict__ Vt) {
    int slot = blockIdx.x * 4 + (threadIdx.x >> 6);
    int d = threadIdx.x & 63;
    int t = slot / 24, c = slot % 24;
    const bf16* base = QKV + (size_t)t * NQKV;
    int off = (c < 16) ? c * 128 : (c < 20) ? 2048 + (c - 16) * 128 : 2560 + (c - 20) * 128;
    float x1 = __bfloat162float(base[off + d]);
    float x2 = __bfloat162float(base[off + 64 + d]);
    float o1, o2;
    if (c < 20) {
        // inv_freq = 10000^(-d/64) = exp(-d * ln(10000)/64)
        float invf = __expf((float)d * -0.14391156831f);
        float ang = (float)t * invf;
        float sn = sinf(ang), cs = cosf(ang);
        o1 = x1 * cs - x2 * sn;
        o2 = x1 * sn + x2 * cs;
    } else {
        o1 = x1;
        o2 = x2;
    }
    if (c < 16) {
        const float scale = 0.12751741f;  // 1/sqrt(128) * log2(e): softmax runs in base-2
        o1 *= scale;
        o2 *= scale;
        bf16* dst = Qs + ((size_t)c * TT + t) * DHD;
        dst[d] = __float2bfloat16(o1);
        dst[d + 64] = __float2bfloat16(o2);
    } else if (c < 20) {
        bf16* dst = Ks + ((size_t)(c - 16) * TT + t) * DHD;
        dst[d] = __float2bfloat16(o1);
        dst[d + 64] = __float2bfloat16(o2);
    } else {
        int gg = c - 20;
        Vt[((size_t)gg * DHD + d) * TT + t] = __float2bfloat16(o1);
        Vt[((size_t)gg * DHD + d + 64) * TT + t] = __float2bfloat16(o2);
    }
}

// ---------------- Flash attention: causal, GQA, BK=64, folded q-tile scheduling ----------------
// Block = 4 waves x 16 q-rows = one 64-row q-tile; block b processes q-tiles {b, 63-b}
// so every block does exactly 65 key-tiles (load balance). Diagonal tiles skip
// fully-masked MFMA n-tiles per wave.
__global__ __launch_bounds__(256, 3) void attn_kernel(const bf16* __restrict__ Qs,
                                                      const bf16* __restrict__ Ks,
                                                      const bf16* __restrict__ Vt,
                                                      bf16* __restrict__ Y) {
    __shared__ bf16 KsL[64][136];    // [key][dh], +8 pad (row stride 68 dwords == 4 mod 32: balanced)
    __shared__ bf16 VtL[128][72];    // [dh][key], +8 pad (36 dwords == 4 mod 32)
    __shared__ bf16 PsL[4][16][72];  // per wave [qrow][key]
    int h = blockIdx.y, bpair = blockIdx.x, g = h >> 2;
    int tid = threadIdx.x, wave = tid >> 6, lane = tid & 63, quad = lane >> 4, l15 = lane & 15;

    const bf16* kg = Ks + (size_t)g * TT * DHD;
    const bf16* vg = Vt + (size_t)g * DHD * TT;
    f32x4 zero = {0.f, 0.f, 0.f, 0.f};

    for (int pass = 0; pass < 2; ++pass) {
        int qt = (pass == 0) ? bpair : 63 - bpair;
        int qbase = qt * 64 + wave * 16;

        short8 qf[4];
        const bf16* qptr = Qs + ((size_t)h * TT + qbase + l15) * DHD + quad * 8;
#pragma unroll
        for (int ks = 0; ks < 4; ++ks) qf[ks] = *(const short8*)(qptr + ks * 32);

        f32x4 acc[8];
#pragma unroll
        for (int i = 0; i < 8; ++i) acc[i] = zero;
        float m_i[4] = {-1e30f, -1e30f, -1e30f, -1e30f};
        float l_i[4] = {0.f, 0.f, 0.f, 0.f};

        for (int kt = 0; kt <= qt; ++kt) {
            int kb = kt * 64;
            bool diag = (kt == qt);
            // ---- global loads to regs (overlap with prior iter's tail + barrier) ----
            short8 kv[4], vv[4];
#pragma unroll
            for (int r = 0; r < 4; ++r) {
                int idx = r * 256 + tid;
                kv[r] = *(const short8*)(kg + (size_t)(kb + (idx >> 4)) * DHD + (idx & 15) * 8);
                vv[r] = *(const short8*)(vg + (size_t)(idx >> 3) * TT + kb + (idx & 7) * 8);
            }
            __syncthreads();  // prior iteration's LDS reads complete
#pragma unroll
            for (int r = 0; r < 4; ++r) {
                int idx = r * 256 + tid;
                *(short8*)&KsL[idx >> 4][(idx & 15) * 8] = kv[r];
                *(short8*)&VtL[idx >> 3][(idx & 7) * 8] = vv[r];
            }
            __syncthreads();

            // ---- S = Q K^T over 4 n-tiles of 16 keys ----
            f32x4 s[4];
#pragma unroll
            for (int nt = 0; nt < 4; ++nt) {
                if (!diag || nt <= wave) {
                    s[nt] = zero;
#pragma unroll
                    for (int ks = 0; ks < 4; ++ks) {
                        short8 b = *(const short8*)&KsL[nt * 16 + l15][ks * 32 + quad * 8];
                        s[nt] = __builtin_amdgcn_mfma_f32_16x16x32_bf16(qf[ks], b, s[nt], 0, 0, 0);
                    }
                    if (diag && nt == wave) {
#pragma unroll
                        for (int r = 0; r < 4; ++r)
                            if (l15 > quad * 4 + r) s[nt][r] = -1e30f;
                    }
                } else {
#pragma unroll
                    for (int r = 0; r < 4; ++r) s[nt][r] = -1e30f;
                }
            }

            // ---- online softmax (base-2; log2e folded into Q) ----
            float alpha[4];
#pragma unroll
            for (int r = 0; r < 4; ++r) {
                float mt = fmaxf(fmaxf(s[0][r], s[1][r]), fmaxf(s[2][r], s[3][r]));
                mt = fmaxf(mt, __shfl_xor(mt, 1, 16));
                mt = fmaxf(mt, __shfl_xor(mt, 2, 16));
                mt = fmaxf(mt, __shfl_xor(mt, 4, 16));
                mt = fmaxf(mt, __shfl_xor(mt, 8, 16));
                float mnew = fmaxf(m_i[r], mt);
                alpha[r] = exp2f(m_i[r] - mnew);
                m_i[r] = mnew;
            }
#pragma unroll
            for (int nt = 0; nt < 4; ++nt)
#pragma unroll
                for (int r = 0; r < 4; ++r) s[nt][r] = exp2f(s[nt][r] - m_i[r]);
#pragma unroll
            for (int r = 0; r < 4; ++r) {
                float rs = (s[0][r] + s[1][r]) + (s[2][r] + s[3][r]);
                rs += __shfl_xor(rs, 1, 16);
                rs += __shfl_xor(rs, 2, 16);
                rs += __shfl_xor(rs, 4, 16);
                rs += __shfl_xor(rs, 8, 16);
                l_i[r] = l_i[r] * alpha[r] + rs;
            }
#pragma unroll
            for (int d8 = 0; d8 < 8; ++d8)
#pragma unroll
                for (int r = 0; r < 4; ++r) acc[d8][r] *= alpha[r];

            // ---- P: C-layout -> LDS -> A-layout (wave-local) ----
#pragma unroll
            for (int nt = 0; nt < 4; ++nt)
#pragma unroll
                for (int r = 0; r < 4; ++r)
                    PsL[wave][quad * 4 + r][nt * 16 + l15] = __float2bfloat16(s[nt][r]);
            asm volatile("s_waitcnt lgkmcnt(0)" ::: "memory");

            // ---- O += P V ----
            int kkmax = diag ? (wave >> 1) + 1 : 2;
#pragma unroll
            for (int kk = 0; kk < 2; ++kk) {
                if (kk < kkmax) {
                    short8 pf = *(const short8*)&PsL[wave][l15][kk * 32 + quad * 8];
#pragma unroll
                    for (int d8 = 0; d8 < 8; ++d8) {
                        short8 b = *(const short8*)&VtL[d8 * 16 + l15][kk * 32 + quad * 8];
                        acc[d8] = __builtin_amdgcn_mfma_f32_16x16x32_bf16(pf, b, acc[d8], 0, 0, 0);
                    }
                }
            }
        }
        // ---- epilogue ----
#pragma unroll
        for (int r = 0; r < 4; ++r) l_i[r] = 1.0f / l_i[r];
#pragma unroll
        for (int d8 = 0; d8 < 8; ++d8)
#pragma unroll
            for (int r = 0; r < 4; ++r) {
                int t = qbase + quad * 4 + r;
                int dh = d8 * 16 + l15;
                Y[(size_t)t * DD + h * DHD + dh] = __float2bfloat16(acc[d8][r] * l_i[r]);
            }
        __syncthreads();  // pass 2 staging must not clobber pass 1 reads
    }
}

extern "C" void kernel_launch(void* const* d_in, const int* in_sizes, int n_in,
                              void* d_out, int out_size, void* d_ws, size_t ws_size,
                              hipStream_t stream) {
    const float* x = (const float*)d_in[0];
    const float* Wq = (const float*)d_in[1];
    const float* Wk = (const float*)d_in[2];
    const float* Wv = (const float*)d_in[3];
    const float* Wo = (const float*)d_in[4];

    char* ws = (char*)d_ws;
    size_t off = 0;
    auto alloc = [&](size_t bytes) {
        void* p = ws + off;
        off += (bytes + 255) & ~(size_t)255;
        return p;
    };
    bf16* xb = (bf16*)alloc((size_t)TT * DD * 2);
    bf16* Wt = (bf16*)alloc((size_t)NQKV * DD * 2);   // [Wq^T | Wk^T | Wv^T] rows, each row K=2048
    bf16* Wot = (bf16*)alloc((size_t)DD * DD * 2);    // Wo^T
    bf16* QKVb = (bf16*)alloc((size_t)TT * NQKV * 2);
    bf16* Qs = (bf16*)alloc((size_t)NH * TT * DHD * 2);
    bf16* Ksb = (bf16*)alloc((size_t)NKV * TT * DHD * 2);
    bf16* Vtb = (bf16*)alloc((size_t)NKV * DHD * TT * 2);
    bf16* Yb = (bf16*)alloc((size_t)TT * DD * 2);

    cast_x_kernel<<<(TT * DD / 4 + 255) / 256, 256, 0, stream>>>(x, xb, TT * DD);
    dim3 tb(32, 8);
    transpose_cast_kernel<<<dim3(DD / 32, DD / 32), tb, 0, stream>>>(Wq, Wt, DD, DD, 0);
    transpose_cast_kernel<<<dim3(DD / 32, 512 / 32), tb, 0, stream>>>(Wk, Wt, DD, 512, 2048);
    transpose_cast_kernel<<<dim3(DD / 32, 512 / 32), tb, 0, stream>>>(Wv, Wt, DD, 512, 2560);
    transpose_cast_kernel<<<dim3(DD / 32, DD / 32), tb, 0, stream>>>(Wo, Wot, DD, DD, 0);

    gemm_bt_kernel<true><<<dim3(NQKV / 128, TT / 128), 256, 0, stream>>>(xb, Wt, QKVb, TT, NQKV, DD);
    rope_split_kernel<<<TT * 24 / 4, 256, 0, stream>>>(QKVb, Qs, Ksb, Vtb);
    attn_kernel<<<dim3(32, NH), 256, 0, stream>>>(Qs, Ksb, Vtb, Yb);
    gemm_bt_kernel<false><<<dim3(DD / 128, TT / 128), 256, 0, stream>>>(Yb, Wot, d_out, TT, DD, DD);
}

// Round 3
// 420.550 us; speedup vs baseline: 1.5568x; 1.0938x over previous
//
#include <hip/hip_runtime.h>
#include <hip/hip_bf16.h>

#define TT 4096
#define DD 2048
#define NH 16
#define NKV 4
#define DHD 128
#define NQKV 3072

typedef __attribute__((ext_vector_type(8))) short short8;
typedef __attribute__((ext_vector_type(4))) float f32x4;
typedef __hip_bfloat16 bf16;

// async global->LDS, 16B per lane; LDS dest = wave-uniform base + lane*16
#define GLOAD_LDS16(g, l)                                                \
    __builtin_amdgcn_global_load_lds(                                    \
        (const __attribute__((address_space(1))) unsigned int*)(g),      \
        (__attribute__((address_space(3))) unsigned int*)(l), 16, 0, 0)

// ---------------- cast x -> bf16 ----------------
__global__ void cast_x_kernel(const float* __restrict__ x, bf16* __restrict__ xb, int n) {
    int i = (blockIdx.x * blockDim.x + threadIdx.x) * 4;
    if (i >= n) return;
    float4 v = *(const float4*)(x + i);
    xb[i + 0] = __float2bfloat16(v.x);
    xb[i + 1] = __float2bfloat16(v.y);
    xb[i + 2] = __float2bfloat16(v.z);
    xb[i + 3] = __float2bfloat16(v.w);
}

// ---------------- all 4 weight transposes in one launch ----------------
__global__ void transpose_cast_all(const float* __restrict__ Wq, const float* __restrict__ Wk,
                                   const float* __restrict__ Wv, const float* __restrict__ Wo,
                                   bf16* __restrict__ Wt, bf16* __restrict__ Wot) {
    __shared__ float tile[32][33];
    const float* in;
    bf16* out;
    int N, rowOff;
    switch (blockIdx.z) {
        case 0: in = Wq; out = Wt; N = 2048; rowOff = 0; break;
        case 1: in = Wk; out = Wt; N = 512; rowOff = 2048; break;
        case 2: in = Wv; out = Wt; N = 512; rowOff = 2560; break;
        default: in = Wo; out = Wot; N = 2048; rowOff = 0; break;
    }
    int n0 = blockIdx.y * 32;
    if (n0 >= N) return;
    int k0 = blockIdx.x * 32;
    int tx = threadIdx.x, ty = threadIdx.y;
#pragma unroll
    for (int i = 0; i < 4; ++i)
        tile[ty + i * 8][tx] = in[(size_t)(k0 + ty + i * 8) * N + n0 + tx];
    __syncthreads();
#pragma unroll
    for (int i = 0; i < 4; ++i)
        out[(size_t)(rowOff + n0 + ty + i * 8) * 2048 + k0 + tx] = __float2bfloat16(tile[tx][ty + i * 8]);
}

// ---------------- GEMM (m97 recipe): A (MxK) bf16, Bt (NxK) bf16, C (MxN) ----------------
template <bool OUT_BF16>
__global__ __launch_bounds__(256) void gemm_bt_kernel(const bf16* __restrict__ A,
                                                      const bf16* __restrict__ Bt,
                                                      void* __restrict__ C,
                                                      int M, int N, int K) {
    __shared__ bf16 As[128 * 32];
    __shared__ bf16 Bs[128 * 32];
    int bn0 = blockIdx.x * 128, bm0 = blockIdx.y * 128;
    int tid = threadIdx.x;
    int wave = tid >> 6, lane = tid & 63, quad = lane >> 4, l15 = lane & 15;
    int wm = (wave >> 1) * 64, wn = (wave & 1) * 64;

    // staging: per wave, 2 insts A (16 rows each) + 2 insts B
    int srow = wave * 32 + (lane >> 2);
    int scol = (lane & 3) * 8;
    const bf16* gA = A + (size_t)(bm0 + srow) * K + scol;
    const bf16* gB = Bt + (size_t)(bn0 + srow) * K + scol;
    bf16* lA = As + srow * 32 + scol;
    bf16* lB = Bs + srow * 32 + scol;

    f32x4 zero = {0.f, 0.f, 0.f, 0.f};
    f32x4 acc[4][4];
#pragma unroll
    for (int i = 0; i < 4; ++i)
#pragma unroll
        for (int j = 0; j < 4; ++j) acc[i][j] = zero;

    for (int k0 = 0; k0 < K; k0 += 32) {
        GLOAD_LDS16(gA + k0, lA);
        GLOAD_LDS16(gA + k0 + (size_t)16 * K, lA + 16 * 32);
        GLOAD_LDS16(gB + k0, lB);
        GLOAD_LDS16(gB + k0 + (size_t)16 * K, lB + 16 * 32);
        __syncthreads();
        short8 af[4], bfr[4];
#pragma unroll
        for (int i = 0; i < 4; ++i) af[i] = *(const short8*)&As[(wm + i * 16 + l15) * 32 + quad * 8];
#pragma unroll
        for (int j = 0; j < 4; ++j) bfr[j] = *(const short8*)&Bs[(wn + j * 16 + l15) * 32 + quad * 8];
#pragma unroll
        for (int i = 0; i < 4; ++i)
#pragma unroll
            for (int j = 0; j < 4; ++j)
                acc[i][j] = __builtin_amdgcn_mfma_f32_16x16x32_bf16(af[i], bfr[j], acc[i][j], 0, 0, 0);
        __syncthreads();
    }
#pragma unroll
    for (int i = 0; i < 4; ++i)
#pragma unroll
        for (int j = 0; j < 4; ++j)
#pragma unroll
            for (int r = 0; r < 4; ++r) {
                int row = bm0 + wm + i * 16 + quad * 4 + r;
                int col = bn0 + wn + j * 16 + l15;
                float v = acc[i][j][r];
                if (OUT_BF16)
                    ((bf16*)C)[(size_t)row * N + col] = __float2bfloat16(v);
                else
                    ((float*)C)[(size_t)row * N + col] = v;
            }
}

// ---------------- RoPE + head split. Q scaled by 1/sqrt(128)*log2(e) ----------------
__global__ void rope_split_kernel(const bf16* __restrict__ QKV, bf16* __restrict__ Qs,
                                  bf16* __restrict__ Ks, bf16* __restrict__ Vt) {
    int slot = blockIdx.x * 4 + (threadIdx.x >> 6);
    int d = threadIdx.x & 63;
    int t = slot / 24, c = slot % 24;
    const bf16* base = QKV + (size_t)t * NQKV;
    int off = (c < 16) ? c * 128 : (c < 20) ? 2048 + (c - 16) * 128 : 2560 + (c - 20) * 128;
    float x1 = __bfloat162float(base[off + d]);
    float x2 = __bfloat162float(base[off + 64 + d]);
    float o1, o2;
    if (c < 20) {
        float invf = __expf((float)d * -0.14391156831f);
        float ang = (float)t * invf;
        float sn = sinf(ang), cs = cosf(ang);
        o1 = x1 * cs - x2 * sn;
        o2 = x1 * sn + x2 * cs;
    } else {
        o1 = x1;
        o2 = x2;
    }
    if (c < 16) {
        const float scale = 0.12751741f;  // 1/sqrt(128) * log2(e)
        o1 *= scale;
        o2 *= scale;
        bf16* dst = Qs + ((size_t)c * TT + t) * DHD;
        dst[d] = __float2bfloat16(o1);
        dst[d + 64] = __float2bfloat16(o2);
    } else if (c < 20) {
        bf16* dst = Ks + ((size_t)(c - 16) * TT + t) * DHD;
        dst[d] = __float2bfloat16(o1);
        dst[d + 64] = __float2bfloat16(o2);
    } else {
        int gg = c - 20;
        Vt[((size_t)gg * DHD + d) * TT + t] = __float2bfloat16(o1);
        Vt[((size_t)gg * DHD + d + 64) * TT + t] = __float2bfloat16(o2);
    }
}

// ---------------- Flash attention: transposed-S, xor-swizzled LDS ----------------
// S^T = K Q^T (swap MFMA operands) -> softmax rows live on lane&15 -> scalar m/l/alpha
// per lane, 2-shfl cross-quad reductions. O^T = V^T P^T; epilogue transposes via LDS.
__global__ __launch_bounds__(256, 4) void attn_kernel(const bf16* __restrict__ Qs,
                                                      const bf16* __restrict__ Ks,
                                                      const bf16* __restrict__ Vt,
                                                      bf16* __restrict__ Y) {
    __shared__ bf16 KsL[64 * 128];    // row=key(64), 16 chunks of 8 bf16; chunk c stored at c^(row&15)
    __shared__ bf16 VtL[128 * 64];    // row=dh(128), 8 chunks; chunk c at c^(row&7)
    __shared__ bf16 PsL[4][16 * 64];  // per wave: row=qrow(16), 8 chunks; chunk c at c^(row&7)
    int h = blockIdx.y, bpair = blockIdx.x, g = h >> 2;
    int tid = threadIdx.x, wave = tid >> 6, lane = tid & 63, quad = lane >> 4, l15 = lane & 15;

    const bf16* kg = Ks + (size_t)g * TT * DHD;
    const bf16* vg = Vt + (size_t)g * DHD * TT;
    f32x4 zero = {0.f, 0.f, 0.f, 0.f};

    for (int pass = 0; pass < 2; ++pass) {
        int qt = (pass == 0) ? bpair : 63 - bpair;
        int qbase = qt * 64 + wave * 16;

        short8 qf[4];
        const bf16* qptr = Qs + ((size_t)h * TT + qbase + l15) * DHD + quad * 8;
#pragma unroll
        for (int ks = 0; ks < 4; ++ks) qf[ks] = *(const short8*)(qptr + ks * 32);

        f32x4 acc[8];
#pragma unroll
        for (int i = 0; i < 8; ++i) acc[i] = zero;
        float m_i = -1e30f, l_i = 0.f;

        for (int kt = 0; kt <= qt; ++kt) {
            int kb = kt * 64;
            bool diag = (kt == qt);
            short8 kv[4], vv[4];
            int krow[4], kc[4], vrow[4], vc[4];
#pragma unroll
            for (int r = 0; r < 4; ++r) {
                int idx = r * 256 + tid;
                krow[r] = idx >> 4;
                kc[r] = idx & 15;
                kv[r] = *(const short8*)(kg + (size_t)(kb + krow[r]) * DHD + kc[r] * 8);
                vrow[r] = idx >> 3;
                vc[r] = idx & 7;
                vv[r] = *(const short8*)(vg + (size_t)vrow[r] * TT + kb + vc[r] * 8);
            }
            __syncthreads();  // prior iter LDS reads / epilogue reads complete
#pragma unroll
            for (int r = 0; r < 4; ++r) {
                *(short8*)&KsL[krow[r] * 128 + ((kc[r] ^ (krow[r] & 15)) * 8)] = kv[r];
                *(short8*)&VtL[vrow[r] * 64 + ((vc[r] ^ (vrow[r] & 7)) * 8)] = vv[r];
            }
            __syncthreads();

            // ---- S^T = K Q^T : A=K frag, B=Q frag ----
            f32x4 s[4];
#pragma unroll
            for (int nt = 0; nt < 4; ++nt) {
                if (!diag || nt <= wave) {
                    s[nt] = zero;
#pragma unroll
                    for (int ks = 0; ks < 4; ++ks) {
                        int ch = (ks * 4 + quad) ^ l15;
                        short8 kf = *(const short8*)&KsL[(nt * 16 + l15) * 128 + ch * 8];
                        s[nt] = __builtin_amdgcn_mfma_f32_16x16x32_bf16(kf, qf[ks], s[nt], 0, 0, 0);
                    }
                    if (diag && nt == wave) {
#pragma unroll
                        for (int r = 0; r < 4; ++r)
                            if (quad * 4 + r > l15) s[nt][r] = -1e30f;
                    }
                } else {
#pragma unroll
                    for (int r = 0; r < 4; ++r) s[nt][r] = -1e30f;
                }
            }

            // ---- online softmax: state per lane (qrow = l15), base-2 ----
            float mloc = -1e30f;
#pragma unroll
            for (int nt = 0; nt < 4; ++nt)
#pragma unroll
                for (int r = 0; r < 4; ++r) mloc = fmaxf(mloc, s[nt][r]);
            mloc = fmaxf(mloc, __shfl_xor(mloc, 16));
            mloc = fmaxf(mloc, __shfl_xor(mloc, 32));
            float mnew = fmaxf(m_i, mloc);
            float alpha = exp2f(m_i - mnew);
            m_i = mnew;
            float sl = 0.f;
#pragma unroll
            for (int nt = 0; nt < 4; ++nt)
#pragma unroll
                for (int r = 0; r < 4; ++r) {
                    s[nt][r] = exp2f(s[nt][r] - mnew);
                    sl += s[nt][r];
                }
            sl += __shfl_xor(sl, 16);
            sl += __shfl_xor(sl, 32);
            l_i = l_i * alpha + sl;
#pragma unroll
            for (int d8 = 0; d8 < 8; ++d8)
#pragma unroll
                for (int r = 0; r < 4; ++r) acc[d8][r] *= alpha;

            // ---- P -> PsL[qrow=l15][key] (swizzled, paired b32 writes) ----
#pragma unroll
            for (int nt = 0; nt < 4; ++nt)
#pragma unroll
                for (int rr = 0; rr < 2; ++rr) {
                    int col = nt * 16 + quad * 4 + rr * 2;
                    int ch = (col >> 3) ^ (l15 & 7);
                    __hip_bfloat162 pk;
                    pk.x = __float2bfloat16(s[nt][rr * 2]);
                    pk.y = __float2bfloat16(s[nt][rr * 2 + 1]);
                    *(__hip_bfloat162*)&PsL[wave][l15 * 64 + ch * 8 + (col & 7)] = pk;
                }
            asm volatile("s_waitcnt lgkmcnt(0)" ::: "memory");

            // ---- O^T += V^T P^T : A=Vt frag, B=P frag ----
            int kkmax = diag ? (wave >> 1) + 1 : 2;
#pragma unroll
            for (int kk = 0; kk < 2; ++kk) {
                if (kk < kkmax) {
                    int chp = (kk * 4 + quad) ^ (l15 & 7);
                    short8 pf = *(const short8*)&PsL[wave][l15 * 64 + chp * 8];
#pragma unroll
                    for (int d8 = 0; d8 < 8; ++d8) {
                        short8 vf = *(const short8*)&VtL[(d8 * 16 + l15) * 64 + chp * 8];
                        acc[d8] = __builtin_amdgcn_mfma_f32_16x16x32_bf16(vf, pf, acc[d8], 0, 0, 0);
                    }
                }
            }
        }

        // ---- epilogue: O^T -> (LDS transpose) -> coalesced Y ----
        float linv = 1.0f / l_i;  // per lane (qrow = l15)
        __syncthreads();          // everyone done with KsL before reuse
        bf16* ow = KsL + wave * 2048;  // 16 rows (qrow) x 128 cols (dh), swizzled chunks
#pragma unroll
        for (int d8 = 0; d8 < 8; ++d8)
#pragma unroll
            for (int rr = 0; rr < 2; ++rr) {
                int colD = d8 * 16 + quad * 4 + rr * 2;
                int ch = (colD >> 3) ^ (l15 & 7);
                __hip_bfloat162 o2;
                o2.x = __float2bfloat16(acc[d8][rr * 2] * linv);
                o2.y = __float2bfloat16(acc[d8][rr * 2 + 1] * linv);
                *(__hip_bfloat162*)&ow[l15 * 128 + ch * 8 + (colD & 7)] = o2;
            }
        asm volatile("s_waitcnt lgkmcnt(0)" ::: "memory");
#pragma unroll
        for (int c = 0; c < 4; ++c) {
            int chunk = quad * 4 + c;
            int ch = chunk ^ (l15 & 7);
            short8 ov = *(const short8*)&ow[l15 * 128 + ch * 8];
            *(short8*)&Y[(size_t)(qbase + l15) * DD + h * DHD + chunk * 8] = ov;
        }
        __syncthreads();  // pass-2 staging must not clobber epilogue reads
    }
}

extern "C" void kernel_launch(void* const* d_in, const int* in_sizes, int n_in,
                              void* d_out, int out_size, void* d_ws, size_t ws_size,
                              hipStream_t stream) {
    const float* x = (const float*)d_in[0];
    const float* Wq = (const float*)d_in[1];
    const float* Wk = (const float*)d_in[2];
    const float* Wv = (const float*)d_in[3];
    const float* Wo = (const float*)d_in[4];

    char* ws = (char*)d_ws;
    size_t off = 0;
    auto alloc = [&](size_t bytes) {
        void* p = ws + off;
        off += (bytes + 255) & ~(size_t)255;
        return p;
    };
    bf16* xb = (bf16*)alloc((size_t)TT * DD * 2);
    bf16* Wt = (bf16*)alloc((size_t)NQKV * DD * 2);
    bf16* Wot = (bf16*)alloc((size_t)DD * DD * 2);
    bf16* QKVb = (bf16*)alloc((size_t)TT * NQKV * 2);
    bf16* Qs = (bf16*)alloc((size_t)NH * TT * DHD * 2);
    bf16* Ksb = (bf16*)alloc((size_t)NKV * TT * DHD * 2);
    bf16* Vtb = (bf16*)alloc((size_t)NKV * DHD * TT * 2);
    bf16* Yb = (bf16*)alloc((size_t)TT * DD * 2);

    cast_x_kernel<<<(TT * DD / 4 + 255) / 256, 256, 0, stream>>>(x, xb, TT * DD);
    transpose_cast_all<<<dim3(64, 64, 4), dim3(32, 8), 0, stream>>>(Wq, Wk, Wv, Wo, Wt, Wot);

    gemm_bt_kernel<true><<<dim3(NQKV / 128, TT / 128), 256, 0, stream>>>(xb, Wt, QKVb, TT, NQKV, DD);
    rope_split_kernel<<<TT * 24 / 4, 256, 0, stream>>>(QKVb, Qs, Ksb, Vtb);
    attn_kernel<<<dim3(32, NH), 256, 0, stream>>>(Qs, Ksb, Vtb, Yb);
    gemm_bt_kernel<false><<<dim3(DD / 128, TT / 128), 256, 0, stream>>>(Yb, Wot, d_out, TT, DD, DD);
}